// Round 1
// baseline (854.775 us; speedup 1.0000x reference)
//
#include <hip/hip_runtime.h>
#include <math.h>

constexpr int C     = 256;
constexpr int DB    = 64;
constexpr int NB    = 16;     // batch
constexpr int LFEAT = 2048;
constexpr int NQ    = 4096;
constexpr int R     = 8;      // rows per block
constexpr float EPS = 1e-6f;

__global__ __launch_bounds__(256, 2)
void semantic_align_fused(const float* __restrict__ feat,
                          const float* __restrict__ qbox,
                          const float* __restrict__ qfeat,
                          const float* __restrict__ posf,
                          const float* __restrict__ c1w1, const float* __restrict__ c1b1,
                          const float* __restrict__ c1w2, const float* __restrict__ c1b2,
                          const float* __restrict__ c1g,  const float* __restrict__ c1be,
                          const float* __restrict__ c2w1, const float* __restrict__ c2b1,
                          const float* __restrict__ c2w2, const float* __restrict__ c2b2,
                          const float* __restrict__ c2g,  const float* __restrict__ c2be,
                          const float* __restrict__ gw1,  const float* __restrict__ gb1,
                          const float* __restrict__ gw2,  const float* __restrict__ gb2,
                          float* __restrict__ out)
{
    __shared__ float s_v[2][R][C];    // phase0-B: v1,v2 ; later s_v[0]=pooled, s_v[1]=gate hidden
    __shared__ float s_sf[R][C];
    __shared__ float s_ef[R][C];
    __shared__ float s_qf[R][C];
    __shared__ float s_u[2][R][C];    // phase B: first 8KB aliased as h-partials
    __shared__ float s_h[2][R][DB];
    __shared__ float s_stat[2][R][2]; // mu, rsqrt(var+eps)
    __shared__ float s_l[R][2];       // gate logits

    const int tid = threadIdx.x;
    const int rowbase = blockIdx.x * R;

    // ---------- Phase 0: gather sf/ef, load pos/qf, v = sf*pos / ef*pos ----------
    for (int r = 0; r < R; ++r) {
        int i = rowbase + r;
        int b = i & (NB - 1);
        int q = i >> 4;
        float cx = qbox[((size_t)b * NQ + q) * 2 + 0];
        float w  = qbox[((size_t)b * NQ + q) * 2 + 1];
        float fs = fminf(fmaxf((cx - 0.5f * w) * (float)LFEAT, 0.f), (float)(LFEAT - 1));
        float fe = fminf(fmaxf((cx + 0.5f * w) * (float)LFEAT, 0.f), (float)(LFEAT - 1));
        int rs = (int)rintf(fs);
        int re = (int)rintf(fe);
        int c = tid;
        float sfv = feat[((size_t)b * LFEAT + rs) * C + c];
        float efv = feat[((size_t)b * LFEAT + re) * C + c];
        float pv  = posf[((size_t)b * NQ + q) * C + c];
        float qv  = qfeat[((size_t)b * NQ + q) * C + c];
        s_sf[r][c] = sfv;
        s_ef[r][c] = efv;
        s_qf[r][c] = qv;
        s_v[0][r][c] = sfv * pv;
        s_v[1][r][c] = efv * pv;
    }
    __syncthreads();

    // ---------- Phase B: h_j[r][d] = relu(v_j . w1_j[d] + b1_j[d]) ----------
    {
        int j = tid >> 7;          // contrast 0/1
        int s = (tid >> 6) & 1;    // c-half
        int d = tid & 63;
        const float* w1 = (j == 0 ? c1w1 : c2w1) + d * C + s * 128;
        float acc[R];
        #pragma unroll
        for (int r = 0; r < R; ++r) acc[r] = 0.f;
        for (int c4 = 0; c4 < 128; c4 += 4) {
            float4 w = *(const float4*)(w1 + c4);
            #pragma unroll
            for (int r = 0; r < R; ++r) {
                float4 v = *(const float4*)(&s_v[j][r][s * 128 + c4]);
                acc[r] += w.x * v.x + w.y * v.y + w.z * v.z + w.w * v.w;
            }
        }
        float* part = &s_u[0][0][0];   // [2][2][R][64] alias
        #pragma unroll
        for (int r = 0; r < R; ++r)
            part[(((j * 2 + s) * R) + r) * 64 + d] = acc[r];
    }
    __syncthreads();
    {
        const float* part = &s_u[0][0][0];
        #pragma unroll
        for (int k = 0; k < 4; ++k) {
            int o = tid + 256 * k;     // 0..1023
            int j = o >> 9;
            int r = (o >> 6) & 7;
            int d = o & 63;
            float h = part[(((j * 2 + 0) * R) + r) * 64 + d]
                    + part[(((j * 2 + 1) * R) + r) * 64 + d]
                    + (j == 0 ? c1b1 : c2b1)[d];
            s_h[j][r][d] = fmaxf(h, 0.f);
        }
    }
    __syncthreads();

    // ---------- Phase C: u_j[r][c] = h_j[r] . w2_j[c] + b2_j[c] ----------
    {
        int c = tid;
        for (int j = 0; j < 2; ++j) {
            const float* w2 = (j == 0 ? c1w2 : c2w2) + c * DB;
            float b2 = (j == 0 ? c1b2 : c2b2)[c];
            float acc[R];
            #pragma unroll
            for (int r = 0; r < R; ++r) acc[r] = 0.f;
            #pragma unroll
            for (int d4 = 0; d4 < DB; d4 += 4) {
                float4 w = *(const float4*)(w2 + d4);
                #pragma unroll
                for (int r = 0; r < R; ++r) {
                    float4 h = *(const float4*)(&s_h[j][r][d4]);
                    acc[r] += w.x * h.x + w.y * h.y + w.z * h.z + w.w * h.w;
                }
            }
            #pragma unroll
            for (int r = 0; r < R; ++r) s_u[j][r][c] = acc[r] + b2;
        }
    }
    __syncthreads();

    // ---------- LN stats: one 16-lane group per (j,r) ----------
    {
        int p = tid >> 4;          // 0..15
        int l = tid & 15;
        int j = p >> 3, r = p & 7;
        float sum = 0.f, sq = 0.f;
        #pragma unroll
        for (int k = 0; k < 16; ++k) {
            float u = s_u[j][r][l + 16 * k];
            sum += u; sq += u * u;
        }
        #pragma unroll
        for (int m = 1; m < 16; m <<= 1) {
            sum += __shfl_xor(sum, m, 16);
            sq  += __shfl_xor(sq,  m, 16);
        }
        if (l == 0) {
            float mu  = sum * (1.f / C);
            float var = sq * (1.f / C) - mu * mu;
            s_stat[j][r][0] = mu;
            s_stat[j][r][1] = rsqrtf(var + EPS);
        }
    }
    __syncthreads();

    // ---------- Phase C3: pooled = 0.5*(sig(ln1)*sf + sig(ln2)*ef) ----------
    {
        int c = tid;
        float g1 = c1g[c], be1 = c1be[c], g2 = c2g[c], be2 = c2be[c];
        #pragma unroll
        for (int r = 0; r < R; ++r) {
            float mu1 = s_stat[0][r][0], rs1 = s_stat[0][r][1];
            float mu2 = s_stat[1][r][0], rs2 = s_stat[1][r][1];
            float ln1 = (s_u[0][r][c] - mu1) * rs1 * g1 + be1;
            float ln2 = (s_u[1][r][c] - mu2) * rs2 * g2 + be2;
            float sg1 = 1.f / (1.f + expf(-ln1));
            float sg2 = 1.f / (1.f + expf(-ln2));
            s_v[0][r][c] = 0.5f * (sg1 * s_sf[r][c] + sg2 * s_ef[r][c]);
        }
    }
    __syncthreads();

    // ---------- Phase D: gate hidden hg[r][t] = relu(x . gw1[t] + gb1[t]) ----------
    {
        int t = tid;
        const float* w = gw1 + (size_t)t * 512;
        float acc[R];
        #pragma unroll
        for (int r = 0; r < R; ++r) acc[r] = 0.f;
        for (int c4 = 0; c4 < C; c4 += 4) {          // x[0:256) = pooled
            float4 wv = *(const float4*)(w + c4);
            #pragma unroll
            for (int r = 0; r < R; ++r) {
                float4 x = *(const float4*)(&s_v[0][r][c4]);
                acc[r] += wv.x * x.x + wv.y * x.y + wv.z * x.z + wv.w * x.w;
            }
        }
        for (int c4 = 0; c4 < C; c4 += 4) {          // x[256:512) = qfeat
            float4 wv = *(const float4*)(w + C + c4);
            #pragma unroll
            for (int r = 0; r < R; ++r) {
                float4 x = *(const float4*)(&s_qf[r][c4]);
                acc[r] += wv.x * x.x + wv.y * x.y + wv.z * x.z + wv.w * x.w;
            }
        }
        float b = gb1[t];
        #pragma unroll
        for (int r = 0; r < R; ++r) s_v[1][r][t] = fmaxf(acc[r] + b, 0.f);
    }
    __syncthreads();

    // ---------- Phase D2: logits ----------
    {
        int p = tid >> 4, l = tid & 15;
        int r = p >> 1, o = p & 1;
        const float* w = gw2 + o * C;
        float sum = 0.f;
        #pragma unroll
        for (int k = 0; k < 16; ++k) {
            int c = l + 16 * k;
            sum += s_v[1][r][c] * w[c];
        }
        #pragma unroll
        for (int m = 1; m < 16; m <<= 1) sum += __shfl_xor(sum, m, 16);
        if (l == 0) s_l[r][o] = sum + gb2[o];
    }
    __syncthreads();

    // ---------- Phase E: gate + store ----------
    {
        int c = tid;
        #pragma unroll
        for (int r = 0; r < R; ++r) {
            float l0 = s_l[r][0], l1 = s_l[r][1];
            float g0 = 1.f / (1.f + expf(l1 - l0));   // softmax over 2
            float g1v = 1.f - g0;
            int i = rowbase + r;
            out[(size_t)i * C + c] = s_v[0][r][c] * g0 + s_qf[r][c] * g1v;
        }
    }
}

extern "C" void kernel_launch(void* const* d_in, const int* in_sizes, int n_in,
                              void* d_out, int out_size, void* d_ws, size_t ws_size,
                              hipStream_t stream) {
    const float* feat  = (const float*)d_in[0];
    const float* qbox  = (const float*)d_in[1];
    const float* qfeat = (const float*)d_in[2];
    const float* posf  = (const float*)d_in[3];
    const float* c1w1  = (const float*)d_in[4];
    const float* c1b1  = (const float*)d_in[5];
    const float* c1w2  = (const float*)d_in[6];
    const float* c1b2  = (const float*)d_in[7];
    const float* c1g   = (const float*)d_in[8];
    const float* c1be  = (const float*)d_in[9];
    const float* c2w1  = (const float*)d_in[10];
    const float* c2b1  = (const float*)d_in[11];
    const float* c2w2  = (const float*)d_in[12];
    const float* c2b2  = (const float*)d_in[13];
    const float* c2g   = (const float*)d_in[14];
    const float* c2be  = (const float*)d_in[15];
    const float* gw1   = (const float*)d_in[16];
    const float* gb1   = (const float*)d_in[17];
    const float* gw2   = (const float*)d_in[18];
    const float* gb2   = (const float*)d_in[19];
    float* out = (float*)d_out;

    const int nrows = NB * NQ;          // 65536
    dim3 grid(nrows / R), block(256);
    semantic_align_fused<<<grid, block, 0, stream>>>(
        feat, qbox, qfeat, posf,
        c1w1, c1b1, c1w2, c1b2, c1g, c1be,
        c2w1, c2b1, c2w2, c2b2, c2g, c2be,
        gw1, gb1, gw2, gb2, out);
}

// Round 2
// 253.565 us; speedup vs baseline: 3.3710x; 3.3710x over previous
//
#include <hip/hip_runtime.h>
#include <hip/hip_bf16.h>
#include <math.h>

typedef __attribute__((ext_vector_type(8))) short bf16x8;
typedef __attribute__((ext_vector_type(4))) float f32x4;

constexpr int NB = 16, NQ = 4096, LF = 2048, C = 256;

__device__ __forceinline__ unsigned short bfbits(float x) {
    return __builtin_bit_cast(unsigned short, __float2bfloat16(x));
}
__device__ __forceinline__ float bf2f(unsigned short u) {
    unsigned v = ((unsigned)u) << 16;
    return __builtin_bit_cast(float, v);
}

// ---- prep: convert weights to bf16, fragment-linear layout in ws ----
// layout: frag index f = (nt*NKS + ks)*64 + lane; element e=0..7
//   ws[off + f*8 + e] = w[nt*16 + (lane&15)][ks*32 + (lane>>4)*8 + e]
// offsets (ushort elems): w1c1=0, w1c2=16384, w2c1=32768, w2c2=49152, gw1=65536
__global__ void prep_weights(const float* __restrict__ c1w1, const float* __restrict__ c2w1,
                             const float* __restrict__ c1w2, const float* __restrict__ c2w2,
                             const float* __restrict__ gw1, unsigned short* __restrict__ ws)
{
    int t = blockIdx.x * 256 + threadIdx.x;          // 0..24575
    const float* src; int K, nks, dstoff, f;
    if (t < 2048)      { src = c1w1; K = 256; nks = 8;  dstoff = 0;      f = t; }
    else if (t < 4096) { src = c2w1; K = 256; nks = 8;  dstoff = 16384;  f = t - 2048; }
    else if (t < 6144) { src = c1w2; K = 64;  nks = 2;  dstoff = 32768;  f = t - 4096; }
    else if (t < 8192) { src = c2w2; K = 64;  nks = 2;  dstoff = 49152;  f = t - 6144; }
    else               { src = gw1;  K = 512; nks = 16; dstoff = 65536;  f = t - 8192; }
    int l = f & 63, s = f >> 6;
    int nt = s / nks, ks = s % nks;
    int n  = nt * 16 + (l & 15);
    int k0 = ks * 32 + (l >> 4) * 8;
    unsigned short* d = ws + dstoff + (size_t)f * 8;
    const float* sp = src + (size_t)n * K + k0;
    #pragma unroll
    for (int e = 0; e < 8; ++e) d[e] = bfbits(sp[e]);
}

// ---- main: wave-autonomous 16-row tiles, no block barriers ----
__global__ __launch_bounds__(256, 2)
void semalign_mfma(const float* __restrict__ feat,  const float* __restrict__ qbox,
                   const float* __restrict__ qfeat, const float* __restrict__ posf,
                   const float* __restrict__ c1b1,  const float* __restrict__ c1b2,
                   const float* __restrict__ c1g,   const float* __restrict__ c1be,
                   const float* __restrict__ c2b1,  const float* __restrict__ c2b2,
                   const float* __restrict__ c2g,   const float* __restrict__ c2be,
                   const float* __restrict__ gb1,   const float* __restrict__ gw2,
                   const float* __restrict__ gb2,
                   const unsigned short* __restrict__ wsb,
                   float* __restrict__ out)
{
    __shared__ __align__(16) unsigned short s_v[4][2][16][256]; // 64 KiB: V1,V2 -> pooled,qf
    __shared__ __align__(16) unsigned short s_h[4][2][16][64];  // 16 KiB: H1,H2 -> gate scalars

    const int tid = threadIdx.x;
    const int l   = tid & 63, wid = tid >> 6;
    const int lr  = l & 15,   lg  = l >> 4;
    const int rowb = blockIdx.x * 64 + wid * 16;
    const int c4 = l * 4;
    const int axor = (lr & 7) << 4;

    char* vbase0 = (char*)&s_v[wid][0][0][0];
    char* vbase1 = (char*)&s_v[wid][1][0][0];
    char* hbase0 = (char*)&s_h[wid][0][0][0];
    char* hbase1 = (char*)&s_h[wid][1][0][0];

    // ---------- phase 0: gather + V = sf*pos / ef*pos -> LDS bf16 (swizzled) ----------
    #pragma unroll 4
    for (int rr = 0; rr < 16; ++rr) {
        int i = rowb + rr, b = i & 15, q = i >> 4;
        float cx = qbox[((size_t)b * NQ + q) * 2 + 0];
        float w  = qbox[((size_t)b * NQ + q) * 2 + 1];
        float fs = fminf(fmaxf((cx - 0.5f * w) * (float)LF, 0.f), (float)(LF - 1));
        float fe = fminf(fmaxf((cx + 0.5f * w) * (float)LF, 0.f), (float)(LF - 1));
        int rs = (int)rintf(fs), re = (int)rintf(fe);
        float4 sf4 = *(const float4*)(feat + ((size_t)b * LF + rs) * C + c4);
        float4 ef4 = *(const float4*)(feat + ((size_t)b * LF + re) * C + c4);
        float4 pf4 = *(const float4*)(posf + ((size_t)b * NQ + q) * C + c4);
        ushort4 v1, v2;
        v1.x = bfbits(sf4.x * pf4.x); v1.y = bfbits(sf4.y * pf4.y);
        v1.z = bfbits(sf4.z * pf4.z); v1.w = bfbits(sf4.w * pf4.w);
        v2.x = bfbits(ef4.x * pf4.x); v2.y = bfbits(ef4.y * pf4.y);
        v2.z = bfbits(ef4.z * pf4.z); v2.w = bfbits(ef4.w * pf4.w);
        int bo = (l * 8) ^ ((rr & 7) << 4);
        *(ushort4*)(vbase0 + rr * 512 + bo) = v1;
        *(ushort4*)(vbase1 + rr * 512 + bo) = v2;
    }
    asm volatile("s_waitcnt lgkmcnt(0)" ::: "memory");

    // ---------- GEMM1: H_j[16x64] = relu(V_j[16x256] @ W1_j^T + b1) ----------
    {
        const unsigned short* w1f[2] = { wsb + 0, wsb + 16384 };
        const float* b1p[2] = { c1b1, c2b1 };
        for (int j = 0; j < 2; ++j) {
            f32x4 acc[4] = {};
            char* ab = j ? vbase1 : vbase0;
            #pragma unroll
            for (int ks = 0; ks < 8; ++ks) {
                bf16x8 a = *(const bf16x8*)(ab + ((lr * 512 + ks * 64 + lg * 16) ^ axor));
                #pragma unroll
                for (int nt = 0; nt < 4; ++nt) {
                    bf16x8 bfr = *(const bf16x8*)(w1f[j] + ((size_t)((nt * 8 + ks) * 64 + l)) * 8);
                    acc[nt] = __builtin_amdgcn_mfma_f32_16x16x32_bf16(a, bfr, acc[nt], 0, 0, 0);
                }
            }
            char* hb = j ? hbase1 : hbase0;
            #pragma unroll
            for (int nt = 0; nt < 4; ++nt) {
                float bv = b1p[j][nt * 16 + lr];
                #pragma unroll
                for (int r = 0; r < 4; ++r) {
                    int row = lg * 4 + r, col = nt * 16 + lr;
                    float h = fmaxf(acc[nt][r] + bv, 0.f);
                    *(unsigned short*)(hb + ((row * 128 + col * 2) ^ ((row & 7) << 4))) = bfbits(h);
                }
            }
        }
    }
    asm volatile("s_waitcnt lgkmcnt(0)" ::: "memory");

    // row pointers for sf/ef re-read (rows in D-fragment layout: row = lg*4+r)
    const float* sfp[2][4];
    #pragma unroll
    for (int r = 0; r < 4; ++r) {
        int i = rowb + lg * 4 + r, b = i & 15, q = i >> 4;
        float cx = qbox[((size_t)b * NQ + q) * 2 + 0];
        float w  = qbox[((size_t)b * NQ + q) * 2 + 1];
        float fs = fminf(fmaxf((cx - 0.5f * w) * (float)LF, 0.f), (float)(LF - 1));
        float fe = fminf(fmaxf((cx + 0.5f * w) * (float)LF, 0.f), (float)(LF - 1));
        sfp[0][r] = feat + ((size_t)b * LF + (int)rintf(fs)) * C;
        sfp[1][r] = feat + ((size_t)b * LF + (int)rintf(fe)) * C;
    }

    // ---------- GEMM2 + LN + sigmoid + pooled (all in D-frag registers) ----------
    f32x4 p[16] = {};
    {
        const unsigned short* w2f[2] = { wsb + 32768, wsb + 49152 };
        const float* b2p[2] = { c1b2, c2b2 };
        const float* gp[2]  = { c1g,  c2g  };
        const float* bep[2] = { c1be, c2be };
        for (int j = 0; j < 2; ++j) {
            f32x4 acc[16] = {};
            char* hb = j ? hbase1 : hbase0;
            #pragma unroll
            for (int ks = 0; ks < 2; ++ks) {
                bf16x8 a = *(const bf16x8*)(hb + ((lr * 128 + ks * 64 + lg * 16) ^ axor));
                #pragma unroll
                for (int nt = 0; nt < 16; ++nt) {
                    bf16x8 bfr = *(const bf16x8*)(w2f[j] + ((size_t)((nt * 2 + ks) * 64 + l)) * 8);
                    acc[nt] = __builtin_amdgcn_mfma_f32_16x16x32_bf16(a, bfr, acc[nt], 0, 0, 0);
                }
            }
            float sum[4] = {0, 0, 0, 0}, sq[4] = {0, 0, 0, 0};
            #pragma unroll
            for (int nt = 0; nt < 16; ++nt) {
                float bv = b2p[j][nt * 16 + lr];
                #pragma unroll
                for (int r = 0; r < 4; ++r) {
                    float u = acc[nt][r] + bv;
                    acc[nt][r] = u;
                    sum[r] += u; sq[r] += u * u;
                }
            }
            #pragma unroll
            for (int r = 0; r < 4; ++r) {
                #pragma unroll
                for (int m = 1; m < 16; m <<= 1) {
                    sum[r] += __shfl_xor(sum[r], m, 16);
                    sq[r]  += __shfl_xor(sq[r],  m, 16);
                }
            }
            float mu[4], rsg[4];
            #pragma unroll
            for (int r = 0; r < 4; ++r) {
                mu[r] = sum[r] * (1.f / 256.f);
                float var = sq[r] * (1.f / 256.f) - mu[r] * mu[r];
                rsg[r] = rsqrtf(var + 1e-6f);
            }
            #pragma unroll
            for (int nt = 0; nt < 16; ++nt) {
                int col = nt * 16 + lr;
                float gv = gp[j][col], bev = bep[j][col];
                #pragma unroll
                for (int r = 0; r < 4; ++r) {
                    float ln = (acc[nt][r] - mu[r]) * rsg[r] * gv + bev;
                    float sg = 1.f / (1.f + __expf(-ln));
                    p[nt][r] += 0.5f * sg * sfp[j][r][col];
                }
            }
        }
    }

    // ---------- stage pooled (bf16) and qf (bf16) into s_v for the gate GEMM ----------
    #pragma unroll
    for (int nt = 0; nt < 16; ++nt) {
        #pragma unroll
        for (int r = 0; r < 4; ++r) {
            int row = lg * 4 + r, col = nt * 16 + lr;
            *(unsigned short*)(vbase0 + ((row * 512 + col * 2) ^ ((row & 7) << 4))) = bfbits(p[nt][r]);
        }
    }
    #pragma unroll 4
    for (int rr = 0; rr < 16; ++rr) {
        int i = rowb + rr, b = i & 15, q = i >> 4;
        float4 qv = *(const float4*)(qfeat + ((size_t)b * NQ + q) * C + c4);
        ushort4 qb4;
        qb4.x = bfbits(qv.x); qb4.y = bfbits(qv.y);
        qb4.z = bfbits(qv.z); qb4.w = bfbits(qv.w);
        *(ushort4*)(vbase1 + rr * 512 + ((l * 8) ^ ((rr & 7) << 4))) = qb4;
    }
    asm volatile("s_waitcnt lgkmcnt(0)" ::: "memory");

    // ---------- gate GEMM: G[16x256] = relu([pooled|qf][16x512] @ GW1^T + gb1) ----------
    f32x4 g[16] = {};
    {
        const unsigned short* gwf = wsb + 65536;
        #pragma unroll
        for (int ks = 0; ks < 16; ++ks) {
            int k0 = ks * 32 + lg * 8;
            char* ab = (k0 & 256) ? vbase1 : vbase0;
            int kk = k0 & 255;
            bf16x8 a = *(const bf16x8*)(ab + ((lr * 512 + kk * 2) ^ axor));
            #pragma unroll
            for (int nt = 0; nt < 16; ++nt) {
                bf16x8 bfr = *(const bf16x8*)(gwf + ((size_t)((nt * 16 + ks) * 64 + l)) * 8);
                g[nt] = __builtin_amdgcn_mfma_f32_16x16x32_bf16(a, bfr, g[nt], 0, 0, 0);
            }
        }
    }

    // ---------- logits + softmax(2) ----------
    {
        float t0[4] = {0, 0, 0, 0}, t1[4] = {0, 0, 0, 0};
        #pragma unroll
        for (int nt = 0; nt < 16; ++nt) {
            int col = nt * 16 + lr;
            float gb = gb1[col];
            float w0 = gw2[col], w1v = gw2[256 + col];
            #pragma unroll
            for (int r = 0; r < 4; ++r) {
                float gv = fmaxf(g[nt][r] + gb, 0.f);
                t0[r] += gv * w0; t1[r] += gv * w1v;
            }
        }
        #pragma unroll
        for (int r = 0; r < 4; ++r) {
            #pragma unroll
            for (int m = 1; m < 16; m <<= 1) {
                t0[r] += __shfl_xor(t0[r], m, 16);
                t1[r] += __shfl_xor(t1[r], m, 16);
            }
        }
        float* s_gate = (float*)&s_h[wid][0][0][0];  // H dead; reuse as per-row gate
        if (lr == 0) {
            float d0 = gb2[0], d1 = gb2[1];
            #pragma unroll
            for (int r = 0; r < 4; ++r) {
                float g0 = 1.f / (1.f + __expf((t1[r] + d1) - (t0[r] + d0)));
                s_gate[lg * 4 + r] = g0;
            }
        }
    }
    asm volatile("s_waitcnt lgkmcnt(0)" ::: "memory");

    // ---------- final: out = pooled*g0 + qf*(1-g0), f32 qf from global ----------
    {
        const float* s_gate = (const float*)&s_h[wid][0][0][0];
        #pragma unroll 4
        for (int rr = 0; rr < 16; ++rr) {
            int i = rowb + rr, b = i & 15, q = i >> 4;
            float g0 = s_gate[rr];
            float g1v = 1.f - g0;
            ushort4 pb = *(const ushort4*)(vbase0 + rr * 512 + ((l * 8) ^ ((rr & 7) << 4)));
            float4 qv = *(const float4*)(qfeat + ((size_t)b * NQ + q) * C + c4);
            float4 o;
            o.x = bf2f(pb.x) * g0 + qv.x * g1v;
            o.y = bf2f(pb.y) * g0 + qv.y * g1v;
            o.z = bf2f(pb.z) * g0 + qv.z * g1v;
            o.w = bf2f(pb.w) * g0 + qv.w * g1v;
            *(float4*)(out + (size_t)i * C + c4) = o;
        }
    }
}

extern "C" void kernel_launch(void* const* d_in, const int* in_sizes, int n_in,
                              void* d_out, int out_size, void* d_ws, size_t ws_size,
                              hipStream_t stream) {
    const float* feat  = (const float*)d_in[0];
    const float* qbox  = (const float*)d_in[1];
    const float* qfeat = (const float*)d_in[2];
    const float* posf  = (const float*)d_in[3];
    const float* c1w1  = (const float*)d_in[4];
    const float* c1b1  = (const float*)d_in[5];
    const float* c1w2  = (const float*)d_in[6];
    const float* c1b2  = (const float*)d_in[7];
    const float* c1g   = (const float*)d_in[8];
    const float* c1be  = (const float*)d_in[9];
    const float* c2w1  = (const float*)d_in[10];
    const float* c2b1  = (const float*)d_in[11];
    const float* c2w2  = (const float*)d_in[12];
    const float* c2b2  = (const float*)d_in[13];
    const float* c2g   = (const float*)d_in[14];
    const float* c2be  = (const float*)d_in[15];
    const float* gw1   = (const float*)d_in[16];
    const float* gb1   = (const float*)d_in[17];
    const float* gw2   = (const float*)d_in[18];
    const float* gb2   = (const float*)d_in[19];
    float* out = (float*)d_out;
    unsigned short* wsb = (unsigned short*)d_ws;  // needs 393216 B

    prep_weights<<<96, 256, 0, stream>>>(c1w1, c2w1, c1w2, c2w2, gw1, wsb);

    const int nrows = NB * NQ;                    // 65536
    dim3 grid(nrows / 64), block(256);
    semalign_mfma<<<grid, block, 0, stream>>>(
        feat, qbox, qfeat, posf,
        c1b1, c1b2, c1g, c1be,
        c2b1, c2b2, c2g, c2be,
        gb1, gw2, gb2, wsb, out);
}

// Round 4
// 194.863 us; speedup vs baseline: 4.3865x; 1.3012x over previous
//
#include <hip/hip_runtime.h>
#include <hip/hip_bf16.h>
#include <math.h>

typedef __attribute__((ext_vector_type(8))) short bf16x8;
typedef __attribute__((ext_vector_type(4))) float f32x4;
typedef __attribute__((ext_vector_type(2))) __fp16 f16x2;
typedef __attribute__((ext_vector_type(4))) unsigned int u32x4;
typedef __attribute__((ext_vector_type(2))) unsigned int u32x2;

constexpr int NB = 16, NQ = 4096, LF = 2048, C = 256;

__device__ __forceinline__ unsigned short bfbits(float x) {
    return __builtin_bit_cast(unsigned short, __float2bfloat16(x));
}
__device__ __forceinline__ unsigned pk2(float a, float b) {
    return (unsigned)bfbits(a) | ((unsigned)bfbits(b) << 16);
}
__device__ __forceinline__ float bflo(unsigned d) { return __builtin_bit_cast(float, d << 16); }
__device__ __forceinline__ float bfhi(unsigned d) { return __builtin_bit_cast(float, d & 0xffff0000u); }

// ---- prep: weights -> bf16 fragment-linear layout in ws (A-frag == old B-frag layout) ----
// ws[off + f*8 + e] = w[nt*16 + (lane&15)][ks*32 + (lane>>4)*8 + e],  f = (nt*NKS+ks)*64 + lane
// offsets (ushort): w1c1=0, w1c2=16384, w2c1=32768, w2c2=49152, gw1=65536  (total 393216 B)
__global__ void prep_weights(const float* __restrict__ c1w1, const float* __restrict__ c2w1,
                             const float* __restrict__ c1w2, const float* __restrict__ c2w2,
                             const float* __restrict__ gw1, unsigned short* __restrict__ ws)
{
    int t = blockIdx.x * 256 + threadIdx.x;          // 0..24575
    const float* src; int K, nks, dstoff, f;
    if (t < 2048)      { src = c1w1; K = 256; nks = 8;  dstoff = 0;      f = t; }
    else if (t < 4096) { src = c2w1; K = 256; nks = 8;  dstoff = 16384;  f = t - 2048; }
    else if (t < 6144) { src = c1w2; K = 64;  nks = 2;  dstoff = 32768;  f = t - 4096; }
    else if (t < 8192) { src = c2w2; K = 64;  nks = 2;  dstoff = 49152;  f = t - 6144; }
    else               { src = gw1;  K = 512; nks = 16; dstoff = 65536;  f = t - 8192; }
    int l = f & 63, s = f >> 6;
    int nt = s / nks, ks = s % nks;
    int n  = nt * 16 + (l & 15);
    int k0 = ks * 32 + (l >> 4) * 8;
    unsigned short* d = ws + dstoff + (size_t)f * 8;
    const float* sp = src + (size_t)n * K + k0;
    #pragma unroll
    for (int e = 0; e < 8; ++e) d[e] = bfbits(sp[e]);
}

// ---- main: swapped-operand MFMA, wave-autonomous, no barriers ----
__global__ __launch_bounds__(256, 3)
void semalign_v3(const float* __restrict__ feat,  const float* __restrict__ qbox,
                 const float* __restrict__ qfeat, const float* __restrict__ posf,
                 const float* __restrict__ c1b1,  const float* __restrict__ c1b2,
                 const float* __restrict__ c1g,   const float* __restrict__ c1be,
                 const float* __restrict__ c2b1,  const float* __restrict__ c2b2,
                 const float* __restrict__ c2g,   const float* __restrict__ c2be,
                 const float* __restrict__ gb1,   const float* __restrict__ gw2,
                 const float* __restrict__ gb2,
                 const unsigned short* __restrict__ wsb,
                 float* __restrict__ out)
{
    __shared__ __align__(16) unsigned short sH[4][2][16][64];   // 16 KiB: per-wave H transpose
    __shared__ __align__(16) unsigned short sP[4][16][256];     // 32 KiB: per-wave pooled transpose

    const int tid = threadIdx.x, l = tid & 63, wid = tid >> 6;
    const int lr = l & 15, lg = l >> 4;
    const int rowb = blockIdx.x * 64 + wid * 16;
    const int q = rowb >> 4;            // wave-uniform query index
    const int b = lr;                   // lane's batch (rowb % 16 == 0)
    const int swz = (lr & 7) << 4;      // XOR byte-swizzle within LDS row

    const float* prow = posf  + ((size_t)b * NQ + q) * C;
    const float* qrow = qfeat + ((size_t)b * NQ + q) * C;
    float cx = qbox[((size_t)b * NQ + q) * 2 + 0];
    float w  = qbox[((size_t)b * NQ + q) * 2 + 1];
    float fs = fminf(fmaxf((cx - 0.5f * w) * (float)LF, 0.f), (float)(LF - 1));
    float fe = fminf(fmaxf((cx + 0.5f * w) * (float)LF, 0.f), (float)(LF - 1));
    const float* srow = feat + ((size_t)b * LF + (int)rintf(fs)) * C;
    const float* erow = feat + ((size_t)b * LF + (int)rintf(fe)) * C;

    // ---------- phase 0: activation B-frags directly from global ----------
    bf16x8 v1f[8], v2f[8];
    #pragma unroll
    for (int ks = 0; ks < 8; ++ks) {
        int k0 = ks * 32 + lg * 8;
        float4 s0 = *(const float4*)(srow + k0), s1 = *(const float4*)(srow + k0 + 4);
        float4 e0 = *(const float4*)(erow + k0), e1 = *(const float4*)(erow + k0 + 4);
        float4 p0 = *(const float4*)(prow + k0), p1 = *(const float4*)(prow + k0 + 4);
        u32x4 a, c;
        a[0] = pk2(s0.x * p0.x, s0.y * p0.y); a[1] = pk2(s0.z * p0.z, s0.w * p0.w);
        a[2] = pk2(s1.x * p1.x, s1.y * p1.y); a[3] = pk2(s1.z * p1.z, s1.w * p1.w);
        c[0] = pk2(e0.x * p0.x, e0.y * p0.y); c[1] = pk2(e0.z * p0.z, e0.w * p0.w);
        c[2] = pk2(e1.x * p1.x, e1.y * p1.y); c[3] = pk2(e1.z * p1.z, e1.w * p1.w);
        v1f[ks] = __builtin_bit_cast(bf16x8, a);
        v2f[ks] = __builtin_bit_cast(bf16x8, c);
    }

    // ---------- GEMM1 (both contrasts interleaved): D[n][row] = W1 . V^T ----------
    {
        f32x4 a1[4] = {}, a2[4] = {};
        #pragma unroll
        for (int ks = 0; ks < 8; ++ks) {
            #pragma unroll
            for (int nt = 0; nt < 4; ++nt) {
                bf16x8 wA = *(const bf16x8*)(wsb + ((size_t)((nt * 8 + ks) * 64 + l)) * 8);
                bf16x8 wB = *(const bf16x8*)(wsb + 16384 + ((size_t)((nt * 8 + ks) * 64 + l)) * 8);
                a1[nt] = __builtin_amdgcn_mfma_f32_16x16x32_bf16(wA, v1f[ks], a1[nt], 0, 0, 0);
                a2[nt] = __builtin_amdgcn_mfma_f32_16x16x32_bf16(wB, v2f[ks], a2[nt], 0, 0, 0);
            }
        }
        char* hb0 = (char*)&sH[wid][0][0][0];
        char* hb1 = (char*)&sH[wid][1][0][0];
        #pragma unroll
        for (int nt = 0; nt < 4; ++nt) {
            float4 b1v = *(const float4*)(c1b1 + nt * 16 + lg * 4);
            float4 b2v = *(const float4*)(c2b1 + nt * 16 + lg * 4);
            u32x2 wv;
            wv[0] = pk2(fmaxf(a1[nt][0] + b1v.x, 0.f), fmaxf(a1[nt][1] + b1v.y, 0.f));
            wv[1] = pk2(fmaxf(a1[nt][2] + b1v.z, 0.f), fmaxf(a1[nt][3] + b1v.w, 0.f));
            *(u32x2*)(hb0 + lr * 128 + ((nt * 32 + lg * 8) ^ swz)) = wv;
            wv[0] = pk2(fmaxf(a2[nt][0] + b2v.x, 0.f), fmaxf(a2[nt][1] + b2v.y, 0.f));
            wv[1] = pk2(fmaxf(a2[nt][2] + b2v.z, 0.f), fmaxf(a2[nt][3] + b2v.w, 0.f));
            *(u32x2*)(hb1 + lr * 128 + ((nt * 32 + lg * 8) ^ swz)) = wv;
        }
    }

    // ---------- GEMM2 + LN + sigmoid + pooled (D layout [n][row=lr]) ----------
    char* pb = (char*)&sP[wid][0][0];
    f16x2 Ph[16][2];
    #pragma unroll
    for (int j = 0; j < 2; ++j) {
        char* hb = (char*)&sH[wid][j][0][0];
        bf16x8 hf0 = *(const bf16x8*)(hb + lr * 128 + ((0 + lg * 16) ^ swz));
        bf16x8 hf1 = *(const bf16x8*)(hb + lr * 128 + ((64 + lg * 16) ^ swz));
        const unsigned short* w2b = wsb + (j ? 49152 : 32768);
        f32x4 u[16] = {};
        #pragma unroll
        for (int nt = 0; nt < 16; ++nt) {
            bf16x8 wA = *(const bf16x8*)(w2b + ((size_t)((nt * 2 + 0) * 64 + l)) * 8);
            bf16x8 wB = *(const bf16x8*)(w2b + ((size_t)((nt * 2 + 1) * 64 + l)) * 8);
            u[nt] = __builtin_amdgcn_mfma_f32_16x16x32_bf16(wA, hf0, u[nt], 0, 0, 0);
            u[nt] = __builtin_amdgcn_mfma_f32_16x16x32_bf16(wB, hf1, u[nt], 0, 0, 0);
        }
        const float* b2p = j ? c2b2 : c1b2;
        const float* gp  = j ? c2g  : c1g;
        const float* bep = j ? c2be : c1be;
        const float* xrow = j ? erow : srow;
        float S = 0.f, Q2 = 0.f;
        #pragma unroll
        for (int nt = 0; nt < 16; ++nt) {
            float4 bv = *(const float4*)(b2p + nt * 16 + lg * 4);
            u[nt][0] += bv.x; u[nt][1] += bv.y; u[nt][2] += bv.z; u[nt][3] += bv.w;
            S  += u[nt][0] + u[nt][1] + u[nt][2] + u[nt][3];
            Q2 += u[nt][0] * u[nt][0] + u[nt][1] * u[nt][1]
                + u[nt][2] * u[nt][2] + u[nt][3] * u[nt][3];
        }
        S  += __shfl_xor(S, 16);  S  += __shfl_xor(S, 32);
        Q2 += __shfl_xor(Q2, 16); Q2 += __shfl_xor(Q2, 32);
        float mu  = S * (1.f / 256.f);
        float rsg = rsqrtf(Q2 * (1.f / 256.f) - mu * mu + 1e-6f);
        #pragma unroll
        for (int nt = 0; nt < 16; ++nt) {
            float4 gv  = *(const float4*)(gp  + nt * 16 + lg * 4);
            float4 bev = *(const float4*)(bep + nt * 16 + lg * 4);
            float4 xv  = *(const float4*)(xrow + nt * 16 + lg * 4);
            float tm[4];
            {
                float g4[4] = { gv.x, gv.y, gv.z, gv.w };
                float e4[4] = { bev.x, bev.y, bev.z, bev.w };
                float x4[4] = { xv.x, xv.y, xv.z, xv.w };
                #pragma unroll
                for (int r = 0; r < 4; ++r) {
                    float ln = (u[nt][r] - mu) * rsg * g4[r] + e4[r];
                    float sg = 1.f / (1.f + __expf(-ln));
                    tm[r] = 0.5f * sg * x4[r];
                }
            }
            if (j == 0) {
                Ph[nt][0] = __builtin_amdgcn_cvt_pkrtz(tm[0], tm[1]);
                Ph[nt][1] = __builtin_amdgcn_cvt_pkrtz(tm[2], tm[3]);
            } else {
                float p0 = (float)Ph[nt][0][0] + tm[0];
                float p1 = (float)Ph[nt][0][1] + tm[1];
                float p2 = (float)Ph[nt][1][0] + tm[2];
                float p3 = (float)Ph[nt][1][1] + tm[3];
                u32x2 wv;
                wv[0] = pk2(p0, p1); wv[1] = pk2(p2, p3);
                *(u32x2*)(pb + lr * 512 + ((nt * 32 + lg * 8) ^ swz)) = wv;
            }
        }
    }

    // ---------- gate GEMM B-frags: pooled (LDS) + qf (global) ----------
    bf16x8 xf[16];
    #pragma unroll
    for (int ks = 0; ks < 8; ++ks)
        xf[ks] = *(const bf16x8*)(pb + lr * 512 + ((ks * 64 + lg * 16) ^ swz));
    #pragma unroll
    for (int ks = 0; ks < 8; ++ks) {
        int k0 = ks * 32 + lg * 8;
        float4 q0 = *(const float4*)(qrow + k0), q1 = *(const float4*)(qrow + k0 + 4);
        u32x4 a;
        a[0] = pk2(q0.x, q0.y); a[1] = pk2(q0.z, q0.w);
        a[2] = pk2(q1.x, q1.y); a[3] = pk2(q1.z, q1.w);
        xf[8 + ks] = __builtin_bit_cast(bf16x8, a);
    }

    // ---------- gate GEMM + logits (streamed weights, 2 acc chains) ----------
    float t0 = 0.f, t1 = 0.f;
    const unsigned short* gwb = wsb + 65536;
    for (int ntp = 0; ntp < 8; ++ntp) {
        f32x4 ga0 = {}, ga1 = {};
        int n0 = ntp * 2, n1 = ntp * 2 + 1;
        #pragma unroll
        for (int kk = 0; kk < 16; ++kk) {
            bf16x8 wA = *(const bf16x8*)(gwb + ((size_t)((n0 * 16 + kk) * 64 + l)) * 8);
            bf16x8 wB = *(const bf16x8*)(gwb + ((size_t)((n1 * 16 + kk) * 64 + l)) * 8);
            ga0 = __builtin_amdgcn_mfma_f32_16x16x32_bf16(wA, xf[kk], ga0, 0, 0, 0);
            ga1 = __builtin_amdgcn_mfma_f32_16x16x32_bf16(wB, xf[kk], ga1, 0, 0, 0);
        }
        #pragma unroll
        for (int t = 0; t < 2; ++t) {
            f32x4 ga = t ? ga1 : ga0;
            int nt = ntp * 2 + t;
            float4 gbv = *(const float4*)(gb1 + nt * 16 + lg * 4);
            float4 w0v = *(const float4*)(gw2 + nt * 16 + lg * 4);
            float4 w1v = *(const float4*)(gw2 + 256 + nt * 16 + lg * 4);
            float gb4[4] = { gbv.x, gbv.y, gbv.z, gbv.w };
            float w04[4] = { w0v.x, w0v.y, w0v.z, w0v.w };
            float w14[4] = { w1v.x, w1v.y, w1v.z, w1v.w };
            #pragma unroll
            for (int r = 0; r < 4; ++r) {
                float hv = fmaxf(ga[r] + gb4[r], 0.f);
                t0 += hv * w04[r]; t1 += hv * w14[r];
            }
        }
    }
    t0 += __shfl_xor(t0, 16); t0 += __shfl_xor(t0, 32);
    t1 += __shfl_xor(t1, 16); t1 += __shfl_xor(t1, 32);
    float g0 = 1.f / (1.f + __expf((t1 + gb2[1]) - (t0 + gb2[0])));
    float g1 = 1.f - g0;

    // ---------- epilogue: out = pooled*g0 + qf*g1, straight from frags ----------
    float* orow = out + (size_t)(rowb + lr) * C;
    #pragma unroll
    for (int ks = 0; ks < 8; ++ks) {
        u32x4 pu = __builtin_bit_cast(u32x4, xf[ks]);
        u32x4 qu = __builtin_bit_cast(u32x4, xf[8 + ks]);
        float4 o0, o1;
        o0.x = bflo(pu[0]) * g0 + bflo(qu[0]) * g1;
        o0.y = bfhi(pu[0]) * g0 + bfhi(qu[0]) * g1;
        o0.z = bflo(pu[1]) * g0 + bflo(qu[1]) * g1;
        o0.w = bfhi(pu[1]) * g0 + bfhi(qu[1]) * g1;
        o1.x = bflo(pu[2]) * g0 + bflo(qu[2]) * g1;
        o1.y = bfhi(pu[2]) * g0 + bfhi(qu[2]) * g1;
        o1.z = bflo(pu[3]) * g0 + bflo(qu[3]) * g1;
        o1.w = bfhi(pu[3]) * g0 + bfhi(qu[3]) * g1;
        *(float4*)(orow + ks * 32 + lg * 8)     = o0;
        *(float4*)(orow + ks * 32 + lg * 8 + 4) = o1;
    }
}

extern "C" void kernel_launch(void* const* d_in, const int* in_sizes, int n_in,
                              void* d_out, int out_size, void* d_ws, size_t ws_size,
                              hipStream_t stream) {
    const float* feat  = (const float*)d_in[0];
    const float* qbox  = (const float*)d_in[1];
    const float* qfeat = (const float*)d_in[2];
    const float* posf  = (const float*)d_in[3];
    const float* c1w1  = (const float*)d_in[4];
    const float* c1b1  = (const float*)d_in[5];
    const float* c1w2  = (const float*)d_in[6];
    const float* c1b2  = (const float*)d_in[7];
    const float* c1g   = (const float*)d_in[8];
    const float* c1be  = (const float*)d_in[9];
    const float* c2w1  = (const float*)d_in[10];
    const float* c2b1  = (const float*)d_in[11];
    const float* c2w2  = (const float*)d_in[12];
    const float* c2b2  = (const float*)d_in[13];
    const float* c2g   = (const float*)d_in[14];
    const float* c2be  = (const float*)d_in[15];
    const float* gw1   = (const float*)d_in[16];
    const float* gb1   = (const float*)d_in[17];
    const float* gw2   = (const float*)d_in[18];
    const float* gb2   = (const float*)d_in[19];
    float* out = (float*)d_out;
    unsigned short* wsb = (unsigned short*)d_ws;   // 393216 B used

    prep_weights<<<96, 256, 0, stream>>>(c1w1, c2w1, c1w2, c2w2, gw1, wsb);

    dim3 grid((NB * NQ) / 64), block(256);         // 1024 blocks, 4 waves each
    semalign_v3<<<grid, block, 0, stream>>>(
        feat, qbox, qfeat, posf,
        c1b1, c1b2, c1g, c1be,
        c2b1, c2b2, c2g, c2be,
        gb1, gw2, gb2, wsb, out);
}